// Round 6
// baseline (289.073 us; speedup 1.0000x reference)
//
#include <hip/hip_runtime.h>

#define N_TOT 8192
#define BHALF 4096
#define D_DIM 512
#define BM 128
#define BK 64
#define NTILE 64          // N_TOT / BM
#define NBLOCKS 2080      // NTILE*(NTILE+1)/2 upper-triangle tiles

typedef float f32x4 __attribute__((ext_vector_type(4)));
typedef short s16x8 __attribute__((ext_vector_type(8)));  // 8 bf16 in 4 VGPRs

__device__ __forceinline__ unsigned short f2bf(float x) {
    union { float f; unsigned int u; } v; v.f = x;
    unsigned int lsb = (v.u >> 16) & 1u;
    unsigned int r = v.u + 0x7fffu + lsb;   // round-to-nearest-even
    return (unsigned short)(r >> 16);
}

// Kernel 1: row L2-normalize [zjs; zis] -> bf16 Z; also zero rowsum + ticket.
__global__ __launch_bounds__(256) void normalize_kernel(
    const float* __restrict__ zis, const float* __restrict__ zjs,
    unsigned short* __restrict__ zb, float* __restrict__ rowsum,
    unsigned int* __restrict__ ctr)
{
    if (blockIdx.x < 32) rowsum[blockIdx.x * 256 + threadIdx.x] = 0.0f;
    if (blockIdx.x == 32 && threadIdx.x == 0) *ctr = 0u;
    int wave = threadIdx.x >> 6;
    int lane = threadIdx.x & 63;
    int row  = blockIdx.x * 4 + wave;
    const float* src = (row < BHALF) ? (zjs + (size_t)row * D_DIM)
                                     : (zis + (size_t)(row - BHALF) * D_DIM);
    const float4* src4 = (const float4*)src;
    float4 v0 = src4[lane * 2];
    float4 v1 = src4[lane * 2 + 1];
    float ss = v0.x*v0.x + v0.y*v0.y + v0.z*v0.z + v0.w*v0.w
             + v1.x*v1.x + v1.y*v1.y + v1.z*v1.z + v1.w*v1.w;
    #pragma unroll
    for (int off = 1; off < 64; off <<= 1) ss += __shfl_xor(ss, off);
    float scale = 1.0f / fmaxf(sqrtf(ss), 1e-8f);

    float vals[8] = {v0.x, v0.y, v0.z, v0.w, v1.x, v1.y, v1.z, v1.w};
    unsigned short u[8];
    #pragma unroll
    for (int i = 0; i < 8; ++i) u[i] = f2bf(vals[i] * scale);
    uint4 o;
    o.x = u[0] | ((unsigned)u[1] << 16);
    o.y = u[2] | ((unsigned)u[3] << 16);
    o.z = u[4] | ((unsigned)u[5] << 16);
    o.w = u[6] | ((unsigned)u[7] << 16);
    ((uint4*)(zb + (size_t)row * D_DIM))[lane] = o;
}

// Kernel 2 (fused): upper-triangle 128x128 tiles of exp(2*Z.Z^T), diag masked,
// row/col sums via symmetry, pos extraction, last-block finalize -> out.
// K-loop is R3's verified structure: BK=64 single-buffer, 8-slot XOR swizzle
// (slot = c8 ^ (row&7): 8 slots x 2 lanes -> free 2-way; conflicts == 0).
// LESSONS: (a) R4: __launch_bounds__(256,5) capped VGPR at 48 -> acc spill ->
// 300 MB scratch traffic, 6x regression. No min-waves clause here.
// (b) R5: BK=32 swizzle collapses to 4 slots (cq&1 ~ cq&3 correlation) ->
// 4-way conflicts + half-cache-line staging reads -> 36x FETCH. Keep BK=64.
__global__ __launch_bounds__(256) void ntxent_fused_kernel(
    const unsigned short* __restrict__ zb, float* __restrict__ rowsum,
    float* __restrict__ pos_ws, unsigned int* __restrict__ ctr,
    float* __restrict__ out)
{
    // Exactly 32 KiB LDS. As/Bs reused as reduction scratch post-loop.
    __shared__ unsigned char smem[32 * 1024];
    unsigned short* As = (unsigned short*)smem;          // 16 KB
    unsigned short* Bs = (unsigned short*)(smem + 16384);// 16 KB

    const int tid  = threadIdx.x;
    const int wave = tid >> 6;
    const int lane = tid & 63;
    const int cq   = lane & 15;
    const int quad = lane >> 4;
    const int wr   = wave >> 1;    // wave row 0..1
    const int wc   = wave & 1;     // wave col 0..1

    // blockIdx -> (I,J), J-group-major (8 J-panels/group), I-major in group.
    int g = 0, rem = blockIdx.x;
    while (rem >= 64 * g + 36) { rem -= 64 * g + 36; ++g; }
    int I, J;
    if (rem < 64 * g) { I = rem >> 3; J = 8 * g + (rem & 7); }
    else {
        rem -= 64 * g;
        int ii = 0;
        while (rem >= 8 - ii) { rem -= 8 - ii; ++ii; }
        I = 8 * g + ii;
        J = I + rem;
    }
    const int rowbase = I * BM;
    const int colbase = J * BM;
    const bool diagblk = (I == J);
    const bool posblk  = (J == I + NTILE / 2);   // contains (i, i+BHALF) pairs

    // Hoisted staging addresses (swizzled k-chunk invariant across rnd/kc).
    const int r0  = tid >> 3;                       // 0..31
    const int c8s = (tid & 7) ^ (r0 & 7);
    const unsigned short* gA[4];
    const unsigned short* gB[4];
    #pragma unroll
    for (int rnd = 0; rnd < 4; ++rnd) {
        int r = rnd * 32 + r0;
        gA[rnd] = zb + (size_t)(rowbase + r) * D_DIM + c8s * 8;
        gB[rnd] = zb + (size_t)(colbase + r) * D_DIM + c8s * 8;
    }

    // Hoisted fragment-read constants.
    int aOff[4], aSw[4], bOff[4], bSw[4];
    #pragma unroll
    for (int t = 0; t < 4; ++t) {
        int ra = wr * 64 + t * 16 + cq;
        int rb = wc * 64 + t * 16 + cq;
        aOff[t] = ra * 64; aSw[t] = ra & 7;
        bOff[t] = rb * 64; bSw[t] = rb & 7;
    }

    f32x4 acc[4][4];
    #pragma unroll
    for (int a = 0; a < 4; ++a)
        #pragma unroll
        for (int b = 0; b < 4; ++b)
            acc[a][b] = (f32x4){0.f, 0.f, 0.f, 0.f};

    for (int kc = 0; kc < D_DIM / BK; ++kc) {
        __syncthreads();   // previous chunk's readers done
        #pragma unroll
        for (int rnd = 0; rnd < 4; ++rnd) {
            __builtin_amdgcn_global_load_lds(
                (const __attribute__((address_space(1))) unsigned int*)gA[rnd],
                (__attribute__((address_space(3))) unsigned int*)&As[(rnd * 256 + tid) * 8],
                16, 0, 0);
            __builtin_amdgcn_global_load_lds(
                (const __attribute__((address_space(1))) unsigned int*)gB[rnd],
                (__attribute__((address_space(3))) unsigned int*)&Bs[(rnd * 256 + tid) * 8],
                16, 0, 0);
            gA[rnd] += BK; gB[rnd] += BK;
        }
        __syncthreads();   // staging complete

        #pragma unroll
        for (int kk = 0; kk < 2; ++kk) {     // two k-steps of 32 per chunk
            s16x8 af[4], bf[4];
            const int c8a = kk * 4 + quad;
            #pragma unroll
            for (int t = 0; t < 4; ++t) {
                af[t] = *(const s16x8*)&As[aOff[t] + ((c8a ^ aSw[t]) << 3)];
                bf[t] = *(const s16x8*)&Bs[bOff[t] + ((c8a ^ bSw[t]) << 3)];
            }
            #pragma unroll
            for (int ar = 0; ar < 4; ++ar)
                #pragma unroll
                for (int bc = 0; bc < 4; ++bc)
                    acc[ar][bc] = __builtin_amdgcn_mfma_f32_16x16x32_bf16(
                        af[ar], bf[bc], acc[ar][bc], 0, 0, 0);
        }
    }

    // pos extraction BEFORE exp: gc == gr + BHALF  <=>  wc==wr, bc==ar, cq==quad*4+reg
    if (posblk && wc == wr) {
        #pragma unroll
        for (int ar = 0; ar < 4; ++ar)
            #pragma unroll
            for (int reg = 0; reg < 4; ++reg)
                if (cq == quad * 4 + reg) {
                    int gr = rowbase + wr * 64 + ar * 16 + quad * 4 + reg;
                    __hip_atomic_store(&pos_ws[gr], acc[ar][ar][reg] * 2.0f,
                                       __ATOMIC_RELAXED, __HIP_MEMORY_SCOPE_AGENT);
                }
    }

    // exp (diag mask only on diagonal blocks)
    #pragma unroll
    for (int ar = 0; ar < 4; ++ar)
        #pragma unroll
        for (int bc = 0; bc < 4; ++bc)
            #pragma unroll
            for (int reg = 0; reg < 4; ++reg)
                acc[ar][bc][reg] = __expf(acc[ar][bc][reg] * 2.0f);
    if (diagblk && wr == wc) {
        #pragma unroll
        for (int ar = 0; ar < 4; ++ar)
            #pragma unroll
            for (int reg = 0; reg < 4; ++reg)
                if (cq == quad * 4 + reg) acc[ar][ar][reg] = 0.0f;
    }

    // ---- LDS reuse: As/Bs dead from here on. ----
    __syncthreads();                       // all MFMA LDS reads complete
    float* red  = (float*)smem;            // [0:128)=rsum, [128:256)=csum
    int*   flag = (int*)(smem + 1024);
    red[tid] = 0.0f;
    __syncthreads();

    // Row sums: sum over 16 cols (bc in-register, cq via shuffle).
    #pragma unroll
    for (int ar = 0; ar < 4; ++ar) {
        float rs[4];
        #pragma unroll
        for (int reg = 0; reg < 4; ++reg) {
            float v = acc[ar][0][reg] + acc[ar][1][reg] + acc[ar][2][reg] + acc[ar][3][reg];
            v += __shfl_xor(v, 1); v += __shfl_xor(v, 2);
            v += __shfl_xor(v, 4); v += __shfl_xor(v, 8);
            rs[reg] = v;
        }
        if (cq == 0) {
            #pragma unroll
            for (int reg = 0; reg < 4; ++reg)
                atomicAdd(&red[wr * 64 + ar * 16 + quad * 4 + reg], rs[reg]);
        }
    }

    // Col sums (symmetry): only for off-diagonal blocks.
    if (!diagblk) {
        #pragma unroll
        for (int bc = 0; bc < 4; ++bc) {
            float cs = 0.0f;
            #pragma unroll
            for (int ar = 0; ar < 4; ++ar)
                #pragma unroll
                for (int reg = 0; reg < 4; ++reg)
                    cs += acc[ar][bc][reg];
            cs += __shfl_xor(cs, 16); cs += __shfl_xor(cs, 32);
            if (quad == 0) atomicAdd(&red[128 + wc * 64 + bc * 16 + cq], cs);
        }
    }

    __syncthreads();
    if (tid < BM) atomicAdd(&rowsum[rowbase + tid], red[tid]);
    else if (!diagblk) atomicAdd(&rowsum[colbase + tid - BM], red[tid]);

    // ---- last-block finalize ----
    __threadfence();
    __syncthreads();
    if (tid == 0) {
        unsigned int t = __hip_atomic_fetch_add(ctr, 1u, __ATOMIC_ACQ_REL,
                                                __HIP_MEMORY_SCOPE_AGENT);
        *flag = (t == NBLOCKS - 1);
    }
    __syncthreads();
    if (*flag) {
        float s = 0.0f;
        for (int r = tid; r < N_TOT; r += 256) {
            float rsv = __hip_atomic_load(&rowsum[r], __ATOMIC_RELAXED,
                                          __HIP_MEMORY_SCOPE_AGENT);
            float pv  = __hip_atomic_load(&pos_ws[r & (BHALF - 1)], __ATOMIC_RELAXED,
                                          __HIP_MEMORY_SCOPE_AGENT);
            s += __logf(rsv) - pv;
        }
        #pragma unroll
        for (int off = 1; off < 64; off <<= 1) s += __shfl_xor(s, off);
        __syncthreads();
        if (lane == 0) red[wave] = s;
        __syncthreads();
        if (tid == 0)
            out[0] = (red[0] + red[1] + red[2] + red[3]) * (1.0f / N_TOT);
    }
}

extern "C" void kernel_launch(void* const* d_in, const int* in_sizes, int n_in,
                              void* d_out, int out_size, void* d_ws, size_t ws_size,
                              hipStream_t stream) {
    const float* zis = (const float*)d_in[0];
    const float* zjs = (const float*)d_in[1];
    float* rowsum = (float*)d_ws;                         // 8192 floats
    float* pos_ws = (float*)d_ws + N_TOT;                 // 4096 floats
    unsigned int* ctr = (unsigned int*)((float*)d_ws + N_TOT + BHALF);
    unsigned short* zb = (unsigned short*)((float*)d_ws + N_TOT + BHALF + 64); // 8 MB
    float* out = (float*)d_out;

    normalize_kernel<<<N_TOT / 4, 256, 0, stream>>>(zis, zjs, zb, rowsum, ctr);
    ntxent_fused_kernel<<<NBLOCKS, 256, 0, stream>>>(zb, rowsum, pos_ws, ctr, out);
}

// Round 7
// 141.440 us; speedup vs baseline: 2.0438x; 2.0438x over previous
//
#include <hip/hip_runtime.h>

#define N_TOT 8192
#define BHALF 4096
#define D_DIM 512
#define BM 128
#define BK 64
#define NTILE 64          // N_TOT / BM
#define NBLOCKS 2080      // NTILE*(NTILE+1)/2 upper-triangle tiles

typedef float f32x4 __attribute__((ext_vector_type(4)));
typedef short s16x8 __attribute__((ext_vector_type(8)));  // 8 bf16 in 4 VGPRs

__device__ __forceinline__ unsigned short f2bf(float x) {
    union { float f; unsigned int u; } v; v.f = x;
    unsigned int lsb = (v.u >> 16) & 1u;
    unsigned int r = v.u + 0x7fffu + lsb;   // round-to-nearest-even
    return (unsigned short)(r >> 16);
}

// Kernel 1: row L2-normalize [zjs; zis] -> bf16 Z; also zero rowsum + ticket.
__global__ __launch_bounds__(256) void normalize_kernel(
    const float* __restrict__ zis, const float* __restrict__ zjs,
    unsigned short* __restrict__ zb, float* __restrict__ rowsum,
    unsigned int* __restrict__ ctr)
{
    if (blockIdx.x < 32) rowsum[blockIdx.x * 256 + threadIdx.x] = 0.0f;
    if (blockIdx.x == 32 && threadIdx.x == 0) *ctr = 0u;
    int wave = threadIdx.x >> 6;
    int lane = threadIdx.x & 63;
    int row  = blockIdx.x * 4 + wave;
    const float* src = (row < BHALF) ? (zjs + (size_t)row * D_DIM)
                                     : (zis + (size_t)(row - BHALF) * D_DIM);
    const float4* src4 = (const float4*)src;
    float4 v0 = src4[lane * 2];
    float4 v1 = src4[lane * 2 + 1];
    float ss = v0.x*v0.x + v0.y*v0.y + v0.z*v0.z + v0.w*v0.w
             + v1.x*v1.x + v1.y*v1.y + v1.z*v1.z + v1.w*v1.w;
    #pragma unroll
    for (int off = 1; off < 64; off <<= 1) ss += __shfl_xor(ss, off);
    float scale = 1.0f / fmaxf(sqrtf(ss), 1e-8f);

    float vals[8] = {v0.x, v0.y, v0.z, v0.w, v1.x, v1.y, v1.z, v1.w};
    unsigned short u[8];
    #pragma unroll
    for (int i = 0; i < 8; ++i) u[i] = f2bf(vals[i] * scale);
    uint4 o;
    o.x = u[0] | ((unsigned)u[1] << 16);
    o.y = u[2] | ((unsigned)u[3] << 16);
    o.z = u[4] | ((unsigned)u[5] << 16);
    o.w = u[6] | ((unsigned)u[7] << 16);
    ((uint4*)(zb + (size_t)row * D_DIM))[lane] = o;
}

// Kernel 2 (fused): upper-triangle 128x128 tiles of exp(2*Z.Z^T), diag masked,
// row/col sums via symmetry, pos extraction, last-block finalize -> out.
// K-loop is R3's verified structure: BK=64 single-buffer, 8-slot XOR swizzle.
// LESSONS:
// (a) R4: __launch_bounds__(256,5) capped VGPR at 48 -> acc spill -> 300 MB
//     scratch traffic, 6x regression. No min-waves clause.
// (b) R5: BK=32 swizzle collapses to 4 slots -> 4-way LDS conflicts + half-
//     cache-line staging. Keep BK=64.
// (c) R6: __threadfence() / ACQ_REL agent atomics per block emit
//     buffer_wbl2+buffer_inv (full L2 wipe, per-XCD serialized) -> 2080 wipes
//     destroyed L2 locality AND throttled the XCDs (250 us). NO agent-scope
//     fences anywhere: __syncthreads()'s vmcnt(0) drain already makes every
//     thread's coherence-point ops (atomicAdd / sc1 stores) globally visible;
//     finalize reads via relaxed agent atomic loads (sc1, L2-bypassing).
__global__ __launch_bounds__(256) void ntxent_fused_kernel(
    const unsigned short* __restrict__ zb, float* __restrict__ rowsum,
    float* __restrict__ pos_ws, unsigned int* __restrict__ ctr,
    float* __restrict__ out)
{
    // Exactly 32 KiB LDS. As/Bs reused as reduction scratch post-loop.
    __shared__ unsigned char smem[32 * 1024];
    unsigned short* As = (unsigned short*)smem;          // 16 KB
    unsigned short* Bs = (unsigned short*)(smem + 16384);// 16 KB

    const int tid  = threadIdx.x;
    const int wave = tid >> 6;
    const int lane = tid & 63;
    const int cq   = lane & 15;
    const int quad = lane >> 4;
    const int wr   = wave >> 1;    // wave row 0..1
    const int wc   = wave & 1;     // wave col 0..1

    // blockIdx -> (I,J), J-group-major (8 J-panels/group), I-major in group.
    int g = 0, rem = blockIdx.x;
    while (rem >= 64 * g + 36) { rem -= 64 * g + 36; ++g; }
    int I, J;
    if (rem < 64 * g) { I = rem >> 3; J = 8 * g + (rem & 7); }
    else {
        rem -= 64 * g;
        int ii = 0;
        while (rem >= 8 - ii) { rem -= 8 - ii; ++ii; }
        I = 8 * g + ii;
        J = I + rem;
    }
    const int rowbase = I * BM;
    const int colbase = J * BM;
    const bool diagblk = (I == J);
    const bool posblk  = (J == I + NTILE / 2);   // contains (i, i+BHALF) pairs

    // Hoisted staging addresses (swizzled k-chunk invariant across rnd/kc).
    const int r0  = tid >> 3;                       // 0..31
    const int c8s = (tid & 7) ^ (r0 & 7);
    const unsigned short* gA[4];
    const unsigned short* gB[4];
    #pragma unroll
    for (int rnd = 0; rnd < 4; ++rnd) {
        int r = rnd * 32 + r0;
        gA[rnd] = zb + (size_t)(rowbase + r) * D_DIM + c8s * 8;
        gB[rnd] = zb + (size_t)(colbase + r) * D_DIM + c8s * 8;
    }

    // Hoisted fragment-read constants.
    int aOff[4], aSw[4], bOff[4], bSw[4];
    #pragma unroll
    for (int t = 0; t < 4; ++t) {
        int ra = wr * 64 + t * 16 + cq;
        int rb = wc * 64 + t * 16 + cq;
        aOff[t] = ra * 64; aSw[t] = ra & 7;
        bOff[t] = rb * 64; bSw[t] = rb & 7;
    }

    f32x4 acc[4][4];
    #pragma unroll
    for (int a = 0; a < 4; ++a)
        #pragma unroll
        for (int b = 0; b < 4; ++b)
            acc[a][b] = (f32x4){0.f, 0.f, 0.f, 0.f};

    for (int kc = 0; kc < D_DIM / BK; ++kc) {
        __syncthreads();   // previous chunk's readers done
        #pragma unroll
        for (int rnd = 0; rnd < 4; ++rnd) {
            __builtin_amdgcn_global_load_lds(
                (const __attribute__((address_space(1))) unsigned int*)gA[rnd],
                (__attribute__((address_space(3))) unsigned int*)&As[(rnd * 256 + tid) * 8],
                16, 0, 0);
            __builtin_amdgcn_global_load_lds(
                (const __attribute__((address_space(1))) unsigned int*)gB[rnd],
                (__attribute__((address_space(3))) unsigned int*)&Bs[(rnd * 256 + tid) * 8],
                16, 0, 0);
            gA[rnd] += BK; gB[rnd] += BK;
        }
        __syncthreads();   // staging complete

        #pragma unroll
        for (int kk = 0; kk < 2; ++kk) {     // two k-steps of 32 per chunk
            s16x8 af[4], bf[4];
            const int c8a = kk * 4 + quad;
            #pragma unroll
            for (int t = 0; t < 4; ++t) {
                af[t] = *(const s16x8*)&As[aOff[t] + ((c8a ^ aSw[t]) << 3)];
                bf[t] = *(const s16x8*)&Bs[bOff[t] + ((c8a ^ bSw[t]) << 3)];
            }
            #pragma unroll
            for (int ar = 0; ar < 4; ++ar)
                #pragma unroll
                for (int bc = 0; bc < 4; ++bc)
                    acc[ar][bc] = __builtin_amdgcn_mfma_f32_16x16x32_bf16(
                        af[ar], bf[bc], acc[ar][bc], 0, 0, 0);
        }
    }

    // pos extraction BEFORE exp: gc == gr + BHALF  <=>  wc==wr, bc==ar, cq==quad*4+reg
    if (posblk && wc == wr) {
        #pragma unroll
        for (int ar = 0; ar < 4; ++ar)
            #pragma unroll
            for (int reg = 0; reg < 4; ++reg)
                if (cq == quad * 4 + reg) {
                    int gr = rowbase + wr * 64 + ar * 16 + quad * 4 + reg;
                    __hip_atomic_store(&pos_ws[gr], acc[ar][ar][reg] * 2.0f,
                                       __ATOMIC_RELAXED, __HIP_MEMORY_SCOPE_AGENT);
                }
    }

    // exp (diag mask only on diagonal blocks)
    #pragma unroll
    for (int ar = 0; ar < 4; ++ar)
        #pragma unroll
        for (int bc = 0; bc < 4; ++bc)
            #pragma unroll
            for (int reg = 0; reg < 4; ++reg)
                acc[ar][bc][reg] = __expf(acc[ar][bc][reg] * 2.0f);
    if (diagblk && wr == wc) {
        #pragma unroll
        for (int ar = 0; ar < 4; ++ar)
            #pragma unroll
            for (int reg = 0; reg < 4; ++reg)
                if (cq == quad * 4 + reg) acc[ar][ar][reg] = 0.0f;
    }

    // ---- LDS reuse: As/Bs dead from here on. ----
    __syncthreads();                       // all MFMA LDS reads complete
    float* red  = (float*)smem;            // [0:128)=rsum, [128:256)=csum
    int*   flag = (int*)(smem + 1024);
    red[tid] = 0.0f;
    __syncthreads();

    // Row sums: sum over 16 cols (bc in-register, cq via shuffle).
    #pragma unroll
    for (int ar = 0; ar < 4; ++ar) {
        float rs[4];
        #pragma unroll
        for (int reg = 0; reg < 4; ++reg) {
            float v = acc[ar][0][reg] + acc[ar][1][reg] + acc[ar][2][reg] + acc[ar][3][reg];
            v += __shfl_xor(v, 1); v += __shfl_xor(v, 2);
            v += __shfl_xor(v, 4); v += __shfl_xor(v, 8);
            rs[reg] = v;
        }
        if (cq == 0) {
            #pragma unroll
            for (int reg = 0; reg < 4; ++reg)
                atomicAdd(&red[wr * 64 + ar * 16 + quad * 4 + reg], rs[reg]);
        }
    }

    // Col sums (symmetry): only for off-diagonal blocks.
    if (!diagblk) {
        #pragma unroll
        for (int bc = 0; bc < 4; ++bc) {
            float cs = 0.0f;
            #pragma unroll
            for (int ar = 0; ar < 4; ++ar)
                #pragma unroll
                for (int reg = 0; reg < 4; ++reg)
                    cs += acc[ar][bc][reg];
            cs += __shfl_xor(cs, 16); cs += __shfl_xor(cs, 32);
            if (quad == 0) atomicAdd(&red[128 + wc * 64 + bc * 16 + cq], cs);
        }
    }

    __syncthreads();
    if (tid < BM) atomicAdd(&rowsum[rowbase + tid], red[tid]);
    else if (!diagblk) atomicAdd(&rowsum[colbase + tid - BM], red[tid]);

    // ---- last-block finalize (NO fences: see lesson (c)) ----
    // The __syncthreads below drains every wave's vmcnt(0): all rowsum
    // atomicAdds and pos sc1-stores are at the coherence point before any
    // thread proceeds; the relaxed ticket RMW is issued after that.
    __syncthreads();
    if (tid == 0) {
        unsigned int t = __hip_atomic_fetch_add(ctr, 1u, __ATOMIC_RELAXED,
                                                __HIP_MEMORY_SCOPE_AGENT);
        *flag = (t == NBLOCKS - 1);
    }
    __syncthreads();
    if (*flag) {
        float s = 0.0f;
        for (int r = tid; r < N_TOT; r += 256) {
            float rsv = __hip_atomic_load(&rowsum[r], __ATOMIC_RELAXED,
                                          __HIP_MEMORY_SCOPE_AGENT);
            float pv  = __hip_atomic_load(&pos_ws[r & (BHALF - 1)], __ATOMIC_RELAXED,
                                          __HIP_MEMORY_SCOPE_AGENT);
            s += __logf(rsv) - pv;
        }
        #pragma unroll
        for (int off = 1; off < 64; off <<= 1) s += __shfl_xor(s, off);
        __syncthreads();
        if (lane == 0) red[wave] = s;
        __syncthreads();
        if (tid == 0)
            out[0] = (red[0] + red[1] + red[2] + red[3]) * (1.0f / N_TOT);
    }
}

extern "C" void kernel_launch(void* const* d_in, const int* in_sizes, int n_in,
                              void* d_out, int out_size, void* d_ws, size_t ws_size,
                              hipStream_t stream) {
    const float* zis = (const float*)d_in[0];
    const float* zjs = (const float*)d_in[1];
    float* rowsum = (float*)d_ws;                         // 8192 floats
    float* pos_ws = (float*)d_ws + N_TOT;                 // 4096 floats
    unsigned int* ctr = (unsigned int*)((float*)d_ws + N_TOT + BHALF);
    unsigned short* zb = (unsigned short*)((float*)d_ws + N_TOT + BHALF + 64); // 8 MB
    float* out = (float*)d_out;

    normalize_kernel<<<N_TOT / 4, 256, 0, stream>>>(zis, zjs, zb, rowsum, ctr);
    ntxent_fused_kernel<<<NBLOCKS, 256, 0, stream>>>(zb, rowsum, pos_ws, ctr, out);
}